// Round 1
// baseline (211.390 us; speedup 1.0000x reference)
//
#include <hip/hip_runtime.h>
#include <math.h>

// Problem constants (match reference)
#define B_N 8
#define A_N 49104
#define M_N 50
#define K_N 80
#define BETA_C (1.0f / 9.0f)

#define APB   192               // anchors per block (192*20 f4 = 3840 = 15*256)
#define NBLK  256               // ceil(A_N/APB); 256*192 = 49152 >= 49104
#define F4PA  20                // float4 per anchor (K=80 / 4)
#define ITER2 15                // phase-2 iterations: APB*F4PA / 256

typedef float vf4 __attribute__((ext_vector_type(4)));

__device__ __forceinline__ float wred(float v) {
#pragma unroll
    for (int off = 32; off > 0; off >>= 1) v += __shfl_down(v, off, 64);
    return v;
}

// Fused kernel: phase 1 = per-anchor assignment + reg loss (192 anchors/block,
// status in LDS); phase 2 = BRANCHLESS focal loss stream over those anchors'
// logits (always-load, ignore-mask folded into the alpha weight, tail-block
// addresses clamped). 2048 blocks = 8 blocks/CU = 32 waves/CU.
// grid = (NBLK, B_N), block = 256
__global__ __launch_bounds__(256, 8) void fused_kernel(
    const float* __restrict__ logits,    // (B, A*K)
    const float* __restrict__ reg,       // (B,A,4)
    const float* __restrict__ anchors,   // (A,4)
    const float* __restrict__ boxes,     // (B,M,4), -1 padded
    const int* __restrict__ classes,     // (B,M)
    float* __restrict__ clspart,         // (B,NBLK)
    float* __restrict__ regpart,         // (B,NBLK)
    float* __restrict__ npospart)        // (B,NBLK)
{
    const int b   = blockIdx.y;
    const int a0  = blockIdx.x * APB;
    const int tid = threadIdx.x;

    __shared__ float sb[M_N * 4];
    __shared__ int   sc[M_N];
    __shared__ int   sstat[APB];
    if (tid < M_N * 4) sb[tid] = boxes[b * M_N * 4 + tid];
    if (tid < M_N)     sc[tid] = classes[b * M_N + tid];
    __syncthreads();

    // ---------------- phase 1: assignment + smooth-L1 ----------------
    float regl = 0.0f;
    float posf = 0.0f;

    if (tid < APB) {
        int s = -1;                      // out-of-range / ignored anchors
        const int a = a0 + tid;
        if (a < A_N) {
            const float4 an = ((const float4*)anchors)[a];
            const float aw = an.z - an.x;
            const float ah = an.w - an.y;
            const float areaA = aw * ah;

            float best = -2.0f;
            int bi = 0;
#pragma unroll 5
            for (int m = 0; m < M_N; ++m) {
                const float bx0 = sb[4 * m + 0];
                const float by0 = sb[4 * m + 1];
                const float bx1 = sb[4 * m + 2];
                const float by1 = sb[4 * m + 3];
                float val = -1.0f;       // masked (invalid) boxes -> -1.0 exactly
                if (bx0 != -1.0f) {
                    const float iw = fmaxf(fminf(an.z, bx1) - fmaxf(an.x, bx0), 0.0f);
                    const float ih = fmaxf(fminf(an.w, by1) - fmaxf(an.y, by0), 0.0f);
                    const float inter = iw * ih;
                    const float ua = fmaxf(areaA + (bx1 - bx0) * (by1 - by0) - inter, 1e-8f);
                    val = inter / ua;
                }
                if (val > best) { best = val; bi = m; }  // strict > == first argmax
            }

            if (best >= 0.5f) {
                s = sc[bi];
                posf = 1.0f;
                const float4 r = ((const float4*)reg)[b * A_N + a];
                const float gx0 = sb[4 * bi + 0], gy0 = sb[4 * bi + 1];
                const float gx1 = sb[4 * bi + 2], gy1 = sb[4 * bi + 3];
                const float acx = an.x + 0.5f * aw;
                const float acy = an.y + 0.5f * ah;
                const float gw0 = gx1 - gx0;
                const float gh0 = gy1 - gy0;
                const float gcx = gx0 + 0.5f * gw0;
                const float gcy = gy0 + 0.5f * gh0;
                const float gw = fmaxf(gw0, 1.0f);
                const float gh = fmaxf(gh0, 1.0f);
                const float t0 = ((gcx - acx) / aw) / 0.1f;
                const float t1 = ((gcy - acy) / ah) / 0.1f;
                const float t2 = logf(gw / aw) / 0.2f;
                const float t3 = logf(gh / ah) / 0.2f;
                float d, sl;
                d = fabsf(t0 - r.x); sl  = (d <= BETA_C) ? 0.5f * d * d / BETA_C : d - 0.5f * BETA_C;
                d = fabsf(t1 - r.y); sl += (d <= BETA_C) ? 0.5f * d * d / BETA_C : d - 0.5f * BETA_C;
                d = fabsf(t2 - r.z); sl += (d <= BETA_C) ? 0.5f * d * d / BETA_C : d - 0.5f * BETA_C;
                d = fabsf(t3 - r.w); sl += (d <= BETA_C) ? 0.5f * d * d / BETA_C : d - 0.5f * BETA_C;
                regl = sl;
            } else if (best < 0.4f) {
                s = 0;
            }
        }
        sstat[tid] = s;
    }
    __syncthreads();

    // ------- phase 2: branchless focal-loss stream over block's logits -------
    // Each iteration: 256 threads read 256 consecutive float4 (4 KB coalesced).
    // No control dependence on status -> loads pipeline freely.
    const vf4* img4 = (const vf4*)(logits + (size_t)b * ((size_t)A_N * K_N));
    float cls = 0.0f;
#pragma unroll 5
    for (int it = 0; it < ITER2; ++it) {
        const int li = it * 256 + tid;        // 0..3839 local float4 index
        const int la = li / F4PA;             // local anchor 0..191
        const int fc = li - la * F4PA;        // float4 column within anchor
        const int st = sstat[la];             // -1 ignore, 0 neg, 1..80 pos class
        const int ga = min(a0 + la, A_N - 1); // clamp tail block (st=-1 masks it)
        const vf4 p4 = __builtin_nontemporal_load(img4 + ((size_t)ga * F4PA + fc));
#pragma unroll
        for (int j = 0; j < 4; ++j) {
            const float p = fminf(fmaxf(p4[j], 1e-4f), 1.0f - 1e-4f);
            const bool ispos = (st >= 1) && (fc * 4 + j == st - 1);
            // pos: 0.25*(1-p)^2*(-log p); neg: 0.75*p^2*(-log(1-p)); ignore: 0
            const float larg = ispos ? p : (1.0f - p);
            const float fw   = 1.0f - larg;
            const float aw   = (st < 0) ? 0.0f : (ispos ? 0.25f : 0.75f);
            cls += aw * fw * fw * (-__logf(larg));  // exact +0.0 when masked
        }
    }

    // ---------------- block reduction ----------------
    const float cw = wred(cls);
    const float rw = wred(regl);
    const float pw = wred(posf);
    __shared__ float sred[12];
    const int lane = tid & 63, wid = tid >> 6;
    if (lane == 0) { sred[wid] = cw; sred[4 + wid] = rw; sred[8 + wid] = pw; }
    __syncthreads();
    if (tid == 0) {
        clspart[b * NBLK + blockIdx.x]  = sred[0] + sred[1] + sred[2] + sred[3];
        regpart[b * NBLK + blockIdx.x]  = sred[4] + sred[5] + sred[6] + sred[7];
        npospart[b * NBLK + blockIdx.x] = sred[8] + sred[9] + sred[10] + sred[11];
    }
}

// Final reduction + normalization. 1 block, 256 threads. Deterministic.
__global__ __launch_bounds__(256) void finalize_kernel(
    const float* __restrict__ clspart,
    const float* __restrict__ regpart,
    const float* __restrict__ npospart,
    float* __restrict__ out)
{
    __shared__ float sred[12];
    float clsAcc = 0.0f, regAcc = 0.0f;  // meaningful on thread 0 only

    for (int b = 0; b < B_N; ++b) {
        float cs = 0.0f, rs = 0.0f, np = 0.0f;
        for (int i = threadIdx.x; i < NBLK; i += 256) {
            cs += clspart[b * NBLK + i];
            rs += regpart[b * NBLK + i];
            np += npospart[b * NBLK + i];
        }
        cs = wred(cs); rs = wred(rs); np = wred(np);
        const int lane = threadIdx.x & 63, wid = threadIdx.x >> 6;
        __syncthreads();                 // protect sred reuse across iterations
        if (lane == 0) { sred[wid] = cs; sred[4 + wid] = rs; sred[8 + wid] = np; }
        __syncthreads();
        if (threadIdx.x == 0) {
            const float csT = sred[0] + sred[1] + sred[2] + sred[3];
            const float rsT = sred[4] + sred[5] + sred[6] + sred[7];
            const float npT = sred[8] + sred[9] + sred[10] + sred[11];
            const float fnp = fmaxf(npT, 1.0f);
            clsAcc += csT / fnp;
            regAcc += rsT / (4.0f * fnp);
        }
    }
    if (threadIdx.x == 0) {
        const float cl = clsAcc / (float)B_N;
        const float rl = regAcc / (float)B_N;
        out[0] = cl;
        out[1] = rl;
        out[2] = cl + rl;
    }
}

extern "C" void kernel_launch(void* const* d_in, const int* in_sizes, int n_in,
                              void* d_out, int out_size, void* d_ws, size_t ws_size,
                              hipStream_t stream) {
    const float* cls_logits = (const float*)d_in[0];  // (B,A,K)
    const float* reg_preds  = (const float*)d_in[1];  // (B,A,4)
    const float* anchors    = (const float*)d_in[2];  // (A,4)
    const float* boxes      = (const float*)d_in[3];  // (B,M,4)
    const int*   classes    = (const int*)d_in[4];    // (B,M)
    float* out = (float*)d_out;

    char* ws = (char*)d_ws;
    float* clspart  = (float*)ws; ws += (size_t)B_N * NBLK * sizeof(float);  // 8 KB
    float* regpart  = (float*)ws; ws += (size_t)B_N * NBLK * sizeof(float);  // 8 KB
    float* npospart = (float*)ws;                                            // 8 KB

    dim3 g1(NBLK, B_N);
    fused_kernel<<<g1, 256, 0, stream>>>(cls_logits, reg_preds, anchors, boxes,
                                         classes, clspart, regpart, npospart);
    finalize_kernel<<<1, 256, 0, stream>>>(clspart, regpart, npospart, out);
}

// Round 2
// 189.502 us; speedup vs baseline: 1.1155x; 1.1155x over previous
//
#include <hip/hip_runtime.h>
#include <math.h>

// Problem constants (match reference)
#define B_N 8
#define A_N 49104
#define M_N 50
#define K_N 80
#define BETA_C (1.0f / 9.0f)

#define APB   192               // anchors per block
#define NBLK  256               // ceil(A_N/APB); 256*192 = 49152 >= 49104
#define F4PA  20                // float4 per anchor (K=80 / 4)
#define ITER2 15                // phase-2 iterations: APB*F4PA / 256
#define PF    5                 // prefetched iterations (overlap phase-1 VALU)

#define C_NEG 0.51986039f       // 0.75 * ln(2): neg focal in log2 form
#define C_POS 0.17328680f       // 0.25 * ln(2): pos focal in log2 form

typedef float vf4 __attribute__((ext_vector_type(4)));

__device__ __forceinline__ float wred(float v) {
#pragma unroll
    for (int off = 32; off > 0; off >>= 1) v += __shfl_down(v, off, 64);
    return v;
}

// Fused kernel. Phase 1 = per-anchor assignment + smooth-L1 (192 anchors/blk).
// Phase 2 = focal loss computed ALL-AS-NEGATIVE (0.75*p^2*(-ln(1-p)), mask
// folded into one fma weight) with a rare correction branch for the positive
// class element. The first PF logit float4s per thread are issued BEFORE
// phase 1 (after the staging barrier) so HBM streams while phase-1 VALU runs;
// the post-phase-1 barrier drains them after they have already landed.
// grid = (NBLK, B_N), block = 256
__global__ __launch_bounds__(256, 6) void fused_kernel(
    const float* __restrict__ logits,    // (B, A*K)
    const float* __restrict__ reg,       // (B,A,4)
    const float* __restrict__ anchors,   // (A,4)
    const float* __restrict__ boxes,     // (B,M,4), -1 padded
    const int* __restrict__ classes,     // (B,M)
    float* __restrict__ clspart,         // (B,NBLK)
    float* __restrict__ regpart,         // (B,NBLK)
    float* __restrict__ npospart)        // (B,NBLK)
{
    const int b   = blockIdx.y;
    const int a0  = blockIdx.x * APB;
    const int tid = threadIdx.x;
    const int a   = a0 + tid;

    __shared__ float4 sb4[M_N];
    __shared__ int    sc[M_N];
    __shared__ int    sstat[APB];

    // ---- tiny staging (barrier here drains ONLY these small loads) ----
    if (tid < M_N) {
        sb4[tid] = ((const float4*)boxes)[b * M_N + tid];
        sc[tid]  = classes[b * M_N + tid];
    }
    const float4 an = ((const float4*)anchors)[min(a, A_N - 1)];
    __syncthreads();

    // ---- prefetch first PF logit float4s: streams during phase-1 VALU ----
    const vf4* img4 = (const vf4*)(logits + (size_t)b * ((size_t)A_N * K_N));
    vf4 pf[PF];
#pragma unroll
    for (int it = 0; it < PF; ++it) {
        const int li = it * 256 + tid;
        const int la = li / F4PA;
        const int fc = li - la * F4PA;
        const int ga = min(a0 + la, A_N - 1);
        pf[it] = __builtin_nontemporal_load(img4 + ((size_t)ga * F4PA + fc));
    }

    // ---------------- phase 1: assignment + smooth-L1 ----------------
    float regl = 0.0f;
    float posf = 0.0f;
    if (tid < APB) {
        int s = -1;                      // out-of-range / ignored anchors
        if (a < A_N) {
            const float aw = an.z - an.x;
            const float ah = an.w - an.y;
            const float areaA = aw * ah;

            float best = -2.0f;
            int bi = 0;
#pragma unroll 2
            for (int m = 0; m < M_N; ++m) {
                const float4 bb = sb4[m];
                float val = -1.0f;       // masked (invalid) boxes -> -1.0 exactly
                if (bb.x != -1.0f) {
                    const float iw = fmaxf(fminf(an.z, bb.z) - fmaxf(an.x, bb.x), 0.0f);
                    const float ih = fmaxf(fminf(an.w, bb.w) - fmaxf(an.y, bb.y), 0.0f);
                    const float inter = iw * ih;
                    const float ua = fmaxf(areaA + (bb.z - bb.x) * (bb.w - bb.y) - inter, 1e-8f);
                    val = inter / ua;    // keep IEEE divide: matches ref argmax
                }
                if (val > best) { best = val; bi = m; }  // strict > == first argmax
            }

            if (best >= 0.5f) {
                s = sc[bi];
                posf = 1.0f;
                const float4 r = ((const float4*)reg)[b * A_N + a];
                const float4 g = sb4[bi];
                const float acx = an.x + 0.5f * aw;
                const float acy = an.y + 0.5f * ah;
                const float gw0 = g.z - g.x;
                const float gh0 = g.w - g.y;
                const float gcx = g.x + 0.5f * gw0;
                const float gcy = g.y + 0.5f * gh0;
                const float gw = fmaxf(gw0, 1.0f);
                const float gh = fmaxf(gh0, 1.0f);
                const float t0 = ((gcx - acx) / aw) / 0.1f;
                const float t1 = ((gcy - acy) / ah) / 0.1f;
                const float t2 = logf(gw / aw) / 0.2f;
                const float t3 = logf(gh / ah) / 0.2f;
                float d, sl;
                d = fabsf(t0 - r.x); sl  = (d <= BETA_C) ? 0.5f * d * d / BETA_C : d - 0.5f * BETA_C;
                d = fabsf(t1 - r.y); sl += (d <= BETA_C) ? 0.5f * d * d / BETA_C : d - 0.5f * BETA_C;
                d = fabsf(t2 - r.z); sl += (d <= BETA_C) ? 0.5f * d * d / BETA_C : d - 0.5f * BETA_C;
                d = fabsf(t3 - r.w); sl += (d <= BETA_C) ? 0.5f * d * d / BETA_C : d - 0.5f * BETA_C;
                regl = sl;
            } else if (best < 0.4f) {
                s = 0;
            }
        }
        sstat[tid] = s;
    }
    __syncthreads();   // drains pf loads too -- they landed during phase 1

    // -------- phase 2: all-as-negative focal + rare positive fixup --------
    float cls = 0.0f;
#define PROC(P4)                                                               \
    {                                                                          \
        const int st = sstat[la];       /* -1 ignore, 0 neg, 1..80 pos */      \
        const float wgt = (st < 0) ? 0.0f : -C_NEG;                            \
        _Pragma("unroll")                                                      \
        for (int j = 0; j < 4; ++j) {                                          \
            const float p  = fminf(fmaxf((P4)[j], 1e-4f), 1.0f - 1e-4f);       \
            const float om = 1.0f - p;                                         \
            const float t  = (p * p) * __log2f(om);   /* t < 0 */              \
            cls = fmaf(wgt, t, cls);                                           \
        }                                                                      \
        if (st >= 1) {                  /* positive anchor (rare) */           \
            const unsigned jo = (unsigned)(st - 1 - 4 * fc);                   \
            if (jo < 4u) {              /* its class lives in this float4 */   \
                const float pj = (jo == 0) ? (P4)[0] : (jo == 1) ? (P4)[1]     \
                               : (jo == 2) ? (P4)[2] : (P4)[3];                \
                const float pc = fminf(fmaxf(pj, 1e-4f), 1.0f - 1e-4f);        \
                const float om = 1.0f - pc;                                    \
                const float t  = (pc * pc) * __log2f(om);                      \
                cls = fmaf(C_NEG, t, cls);                 /* undo neg term */ \
                cls = fmaf((C_POS * om) * om, -__log2f(pc), cls); /* pos */    \
            }                                                                  \
        }                                                                      \
    }

#pragma unroll
    for (int it = 0; it < PF; ++it) {
        const int li = it * 256 + tid;
        const int la = li / F4PA;
        const int fc = li - la * F4PA;
        PROC(pf[it]);
    }
#pragma unroll 5
    for (int it = PF; it < ITER2; ++it) {
        const int li = it * 256 + tid;
        const int la = li / F4PA;
        const int fc = li - la * F4PA;
        const int ga = min(a0 + la, A_N - 1);
        const vf4 p4 = __builtin_nontemporal_load(img4 + ((size_t)ga * F4PA + fc));
        PROC(p4);
    }
#undef PROC

    // ---------------- block reduction ----------------
    const float cw = wred(cls);
    const float rw = wred(regl);
    const float pw = wred(posf);
    __shared__ float sred[12];
    const int lane = tid & 63, wid = tid >> 6;
    if (lane == 0) { sred[wid] = cw; sred[4 + wid] = rw; sred[8 + wid] = pw; }
    __syncthreads();
    if (tid == 0) {
        clspart[b * NBLK + blockIdx.x]  = sred[0] + sred[1] + sred[2] + sred[3];
        regpart[b * NBLK + blockIdx.x]  = sred[4] + sred[5] + sred[6] + sred[7];
        npospart[b * NBLK + blockIdx.x] = sred[8] + sred[9] + sred[10] + sred[11];
    }
}

// Final reduction + normalization. 1 block, 256 threads = 8 batches x 32
// lanes in ONE pass (was 8 serial rounds). Deterministic.
__global__ __launch_bounds__(256) void finalize_kernel(
    const float* __restrict__ clspart,
    const float* __restrict__ regpart,
    const float* __restrict__ npospart,
    float* __restrict__ out)
{
    const int tid = threadIdx.x;
    const int bb  = tid >> 5;            // batch 0..7
    const int l5  = tid & 31;            // lane within batch group
    float cs = 0.0f, rs = 0.0f, np = 0.0f;
#pragma unroll
    for (int i = 0; i < NBLK / 32; ++i) {
        const int idx = bb * NBLK + l5 + i * 32;
        cs += clspart[idx];
        rs += regpart[idx];
        np += npospart[idx];
    }
#pragma unroll
    for (int off = 16; off > 0; off >>= 1) {  // reduce within 32-lane group
        cs += __shfl_down(cs, off, 32);
        rs += __shfl_down(rs, off, 32);
        np += __shfl_down(np, off, 32);
    }
    __shared__ float scs[B_N], srs[B_N], snp[B_N];
    if (l5 == 0) { scs[bb] = cs; srs[bb] = rs; snp[bb] = np; }
    __syncthreads();
    if (tid == 0) {
        float clsAcc = 0.0f, regAcc = 0.0f;
#pragma unroll
        for (int i = 0; i < B_N; ++i) {
            const float fnp = fmaxf(snp[i], 1.0f);
            clsAcc += scs[i] / fnp;
            regAcc += srs[i] / (4.0f * fnp);
        }
        const float cl = clsAcc / (float)B_N;
        const float rl = regAcc / (float)B_N;
        out[0] = cl;
        out[1] = rl;
        out[2] = cl + rl;
    }
}

extern "C" void kernel_launch(void* const* d_in, const int* in_sizes, int n_in,
                              void* d_out, int out_size, void* d_ws, size_t ws_size,
                              hipStream_t stream) {
    const float* cls_logits = (const float*)d_in[0];  // (B,A,K)
    const float* reg_preds  = (const float*)d_in[1];  // (B,A,4)
    const float* anchors    = (const float*)d_in[2];  // (A,4)
    const float* boxes      = (const float*)d_in[3];  // (B,M,4)
    const int*   classes    = (const int*)d_in[4];    // (B,M)
    float* out = (float*)d_out;

    char* ws = (char*)d_ws;
    float* clspart  = (float*)ws; ws += (size_t)B_N * NBLK * sizeof(float);  // 8 KB
    float* regpart  = (float*)ws; ws += (size_t)B_N * NBLK * sizeof(float);  // 8 KB
    float* npospart = (float*)ws;                                            // 8 KB

    dim3 g1(NBLK, B_N);
    fused_kernel<<<g1, 256, 0, stream>>>(cls_logits, reg_preds, anchors, boxes,
                                         classes, clspart, regpart, npospart);
    finalize_kernel<<<1, 256, 0, stream>>>(clspart, regpart, npospart, out);
}

// Round 3
// 183.994 us; speedup vs baseline: 1.1489x; 1.0299x over previous
//
#include <hip/hip_runtime.h>
#include <math.h>

// Problem constants (match reference)
#define B_N 8
#define A_N 49104
#define M_N 50
#define K_N 80
#define BETA_C (1.0f / 9.0f)

#define APB   192               // anchors per block
#define NBLK  256               // ceil(A_N/APB); 256*192 = 49152 >= 49104
#define F4PA  20                // float4 per anchor (K=80 / 4)
#define ITER2 15                // phase-2 iterations: APB*F4PA / 256
#define PF    5                 // prefetched iterations (overlap phase-1 VALU)

#define C_NEG 0.51986039f       // 0.75 * ln(2): neg focal in log2 form
#define C_POS 0.17328680f       // 0.25 * ln(2): pos focal in log2 form

typedef float vf4 __attribute__((ext_vector_type(4)));

__device__ __forceinline__ float wred(float v) {
#pragma unroll
    for (int off = 32; off > 0; off >>= 1) v += __shfl_down(v, off, 64);
    return v;
}

// Fused kernel. Phase 1 = per-anchor assignment + smooth-L1 (192 anchors/blk)
// over the VALID-PREFIX of boxes only (reference pads at the end; nv derived
// per-wave via ballot, no extra barrier; invalid boxes score -1.0 in ref so
// first-argmax over the prefix is identical; nv==0 -> best=-2 -> background,
// matching ref's all-invalid case). Per-box areas precomputed during staging.
// Phase 2 = focal loss ALL-AS-NEGATIVE (0.75*p^2*(-ln(1-p)), mask folded into
// one fma weight) with a rare correction branch for the positive class.
// First PF logit float4s issued BEFORE phase 1 so HBM streams under the
// (now ~2.4x cheaper) phase-1 VALU.
// grid = (NBLK, B_N), block = 256
__global__ __launch_bounds__(256, 6) void fused_kernel(
    const float* __restrict__ logits,    // (B, A*K)
    const float* __restrict__ reg,       // (B,A,4)
    const float* __restrict__ anchors,   // (A,4)
    const float* __restrict__ boxes,     // (B,M,4), -1 padded (suffix)
    const int* __restrict__ classes,     // (B,M)
    float* __restrict__ clspart,         // (B,NBLK)
    float* __restrict__ regpart,         // (B,NBLK)
    float* __restrict__ npospart)        // (B,NBLK)
{
    const int b   = blockIdx.y;
    const int a0  = blockIdx.x * APB;
    const int tid = threadIdx.x;
    const int a   = a0 + tid;

    __shared__ float4 sb4[M_N];
    __shared__ float  sarea[M_N];
    __shared__ int    sc[M_N];
    __shared__ int    sstat[APB];

    // ---- tiny staging (barrier here drains ONLY these small loads) ----
    if (tid < M_N) {
        const float4 bb = ((const float4*)boxes)[b * M_N + tid];
        sb4[tid]   = bb;
        sarea[tid] = (bb.z - bb.x) * (bb.w - bb.y);
        sc[tid]    = classes[b * M_N + tid];
    }
    const float4 an = ((const float4*)anchors)[min(a, A_N - 1)];
    __syncthreads();

    // ---- prefetch first PF logit float4s: streams during phase-1 VALU ----
    const vf4* img4 = (const vf4*)(logits + (size_t)b * ((size_t)A_N * K_N));
    vf4 pf[PF];
#pragma unroll
    for (int it = 0; it < PF; ++it) {
        const int li = it * 256 + tid;
        const int la = li / F4PA;
        const int fc = li - la * F4PA;
        const int ga = min(a0 + la, A_N - 1);
        pf[it] = __builtin_nontemporal_load(img4 + ((size_t)ga * F4PA + fc));
    }

    // ---- valid-prefix length, computed redundantly per wave (no barrier) ----
    const int lane64 = tid & 63;
    const bool vlane = (lane64 < M_N) && (sb4[lane64].x != -1.0f);
    const unsigned long long vmask = __ballot(vlane);
    const int nv = (int)__builtin_ctzll(~vmask | (1ull << M_N)); // first invalid

    // ---------------- phase 1: assignment + smooth-L1 ----------------
    float regl = 0.0f;
    float posf = 0.0f;
    if (tid < APB) {
        int s = -1;                      // out-of-range / ignored anchors
        if (a < A_N) {
            const float aw = an.z - an.x;
            const float ah = an.w - an.y;
            const float areaA = aw * ah;

            float best = -2.0f;
            int bi = 0;
#pragma unroll 2
            for (int m = 0; m < nv; ++m) {
                const float4 bb = sb4[m];
                const float iw = fmaxf(fminf(an.z, bb.z) - fmaxf(an.x, bb.x), 0.0f);
                const float ih = fmaxf(fminf(an.w, bb.w) - fmaxf(an.y, bb.y), 0.0f);
                const float inter = iw * ih;
                const float ua = fmaxf(areaA + sarea[m] - inter, 1e-8f);
                const float val = inter / ua;   // IEEE divide: matches ref argmax
                if (val > best) { best = val; bi = m; }  // strict > == first argmax
            }

            if (best >= 0.5f) {
                s = sc[bi];
                posf = 1.0f;
                const float4 r = ((const float4*)reg)[b * A_N + a];
                const float4 g = sb4[bi];
                const float acx = an.x + 0.5f * aw;
                const float acy = an.y + 0.5f * ah;
                const float gw0 = g.z - g.x;
                const float gh0 = g.w - g.y;
                const float gcx = g.x + 0.5f * gw0;
                const float gcy = g.y + 0.5f * gh0;
                const float gw = fmaxf(gw0, 1.0f);
                const float gh = fmaxf(gh0, 1.0f);
                const float t0 = ((gcx - acx) / aw) / 0.1f;
                const float t1 = ((gcy - acy) / ah) / 0.1f;
                const float t2 = logf(gw / aw) / 0.2f;
                const float t3 = logf(gh / ah) / 0.2f;
                float d, sl;
                d = fabsf(t0 - r.x); sl  = (d <= BETA_C) ? 0.5f * d * d / BETA_C : d - 0.5f * BETA_C;
                d = fabsf(t1 - r.y); sl += (d <= BETA_C) ? 0.5f * d * d / BETA_C : d - 0.5f * BETA_C;
                d = fabsf(t2 - r.z); sl += (d <= BETA_C) ? 0.5f * d * d / BETA_C : d - 0.5f * BETA_C;
                d = fabsf(t3 - r.w); sl += (d <= BETA_C) ? 0.5f * d * d / BETA_C : d - 0.5f * BETA_C;
                regl = sl;
            } else if (best < 0.4f) {
                s = 0;
            }
        }
        sstat[tid] = s;
    }
    __syncthreads();   // drains pf loads too -- they landed during phase 1

    // -------- phase 2: all-as-negative focal + rare positive fixup --------
    float cls = 0.0f;
#define PROC(P4)                                                               \
    {                                                                          \
        const int st = sstat[la];       /* -1 ignore, 0 neg, 1..80 pos */      \
        const float wgt = (st < 0) ? 0.0f : -C_NEG;                            \
        _Pragma("unroll")                                                      \
        for (int j = 0; j < 4; ++j) {                                          \
            const float p  = fminf(fmaxf((P4)[j], 1e-4f), 1.0f - 1e-4f);       \
            const float om = 1.0f - p;                                         \
            const float t  = (p * p) * __log2f(om);   /* t < 0 */              \
            cls = fmaf(wgt, t, cls);                                           \
        }                                                                      \
        if (st >= 1) {                  /* positive anchor (rare) */           \
            const unsigned jo = (unsigned)(st - 1 - 4 * fc);                   \
            if (jo < 4u) {              /* its class lives in this float4 */   \
                const float pj = (jo == 0) ? (P4)[0] : (jo == 1) ? (P4)[1]     \
                               : (jo == 2) ? (P4)[2] : (P4)[3];                \
                const float pc = fminf(fmaxf(pj, 1e-4f), 1.0f - 1e-4f);        \
                const float om = 1.0f - pc;                                    \
                const float t  = (pc * pc) * __log2f(om);                      \
                cls = fmaf(C_NEG, t, cls);                 /* undo neg term */ \
                cls = fmaf((C_POS * om) * om, -__log2f(pc), cls); /* pos */    \
            }                                                                  \
        }                                                                      \
    }

#pragma unroll
    for (int it = 0; it < PF; ++it) {
        const int li = it * 256 + tid;
        const int la = li / F4PA;
        const int fc = li - la * F4PA;
        PROC(pf[it]);
    }
#pragma unroll 5
    for (int it = PF; it < ITER2; ++it) {
        const int li = it * 256 + tid;
        const int la = li / F4PA;
        const int fc = li - la * F4PA;
        const int ga = min(a0 + la, A_N - 1);
        const vf4 p4 = __builtin_nontemporal_load(img4 + ((size_t)ga * F4PA + fc));
        PROC(p4);
    }
#undef PROC

    // ---------------- block reduction ----------------
    const float cw = wred(cls);
    const float rw = wred(regl);
    const float pw = wred(posf);
    __shared__ float sred[12];
    const int lane = tid & 63, wid = tid >> 6;
    if (lane == 0) { sred[wid] = cw; sred[4 + wid] = rw; sred[8 + wid] = pw; }
    __syncthreads();
    if (tid == 0) {
        clspart[b * NBLK + blockIdx.x]  = sred[0] + sred[1] + sred[2] + sred[3];
        regpart[b * NBLK + blockIdx.x]  = sred[4] + sred[5] + sred[6] + sred[7];
        npospart[b * NBLK + blockIdx.x] = sred[8] + sred[9] + sred[10] + sred[11];
    }
}

// Final reduction + normalization. 1 block, 256 threads = 8 batches x 32
// lanes in ONE pass. Deterministic.
__global__ __launch_bounds__(256) void finalize_kernel(
    const float* __restrict__ clspart,
    const float* __restrict__ regpart,
    const float* __restrict__ npospart,
    float* __restrict__ out)
{
    const int tid = threadIdx.x;
    const int bb  = tid >> 5;            // batch 0..7
    const int l5  = tid & 31;            // lane within batch group
    float cs = 0.0f, rs = 0.0f, np = 0.0f;
#pragma unroll
    for (int i = 0; i < NBLK / 32; ++i) {
        const int idx = bb * NBLK + l5 + i * 32;
        cs += clspart[idx];
        rs += regpart[idx];
        np += npospart[idx];
    }
#pragma unroll
    for (int off = 16; off > 0; off >>= 1) {  // reduce within 32-lane group
        cs += __shfl_down(cs, off, 32);
        rs += __shfl_down(rs, off, 32);
        np += __shfl_down(np, off, 32);
    }
    __shared__ float scs[B_N], srs[B_N], snp[B_N];
    if (l5 == 0) { scs[bb] = cs; srs[bb] = rs; snp[bb] = np; }
    __syncthreads();
    if (tid == 0) {
        float clsAcc = 0.0f, regAcc = 0.0f;
#pragma unroll
        for (int i = 0; i < B_N; ++i) {
            const float fnp = fmaxf(snp[i], 1.0f);
            clsAcc += scs[i] / fnp;
            regAcc += srs[i] / (4.0f * fnp);
        }
        const float cl = clsAcc / (float)B_N;
        const float rl = regAcc / (float)B_N;
        out[0] = cl;
        out[1] = rl;
        out[2] = cl + rl;
    }
}

extern "C" void kernel_launch(void* const* d_in, const int* in_sizes, int n_in,
                              void* d_out, int out_size, void* d_ws, size_t ws_size,
                              hipStream_t stream) {
    const float* cls_logits = (const float*)d_in[0];  // (B,A,K)
    const float* reg_preds  = (const float*)d_in[1];  // (B,A,4)
    const float* anchors    = (const float*)d_in[2];  // (A,4)
    const float* boxes      = (const float*)d_in[3];  // (B,M,4)
    const int*   classes    = (const int*)d_in[4];    // (B,M)
    float* out = (float*)d_out;

    char* ws = (char*)d_ws;
    float* clspart  = (float*)ws; ws += (size_t)B_N * NBLK * sizeof(float);  // 8 KB
    float* regpart  = (float*)ws; ws += (size_t)B_N * NBLK * sizeof(float);  // 8 KB
    float* npospart = (float*)ws;                                            // 8 KB

    dim3 g1(NBLK, B_N);
    fused_kernel<<<g1, 256, 0, stream>>>(cls_logits, reg_preds, anchors, boxes,
                                         classes, clspart, regpart, npospart);
    finalize_kernel<<<1, 256, 0, stream>>>(clspart, regpart, npospart, out);
}